// Round 11
// baseline (102.018 us; speedup 1.0000x reference)
//
#include <hip/hip_runtime.h>

namespace {

constexpr int NSC  = 512;   // subcarriers
constexpr int CP   = 7;     // cyclic prefix
constexpr int NTOT = 519;   // N + CP
constexpr int NB   = 2;     // batches per block (software pipeline depth)

// pad every 16 slots by 1 (works for float2 and float4 granularity)
__device__ __forceinline__ int p2(int x) { return x + (x >> 4); }
__device__ __forceinline__ int p4(int x) { return x + (x >> 4); }

struct cf { float x, y; };
__device__ __forceinline__ cf cadd(cf a, cf b) { return {a.x + b.x, a.y + b.y}; }
__device__ __forceinline__ cf csub(cf a, cf b) { return {a.x - b.x, a.y - b.y}; }
__device__ __forceinline__ cf cmul(cf a, cf b) { return {a.x*b.x - a.y*b.y, a.x*b.y + a.y*b.x}; }
__device__ __forceinline__ cf mni(cf a) { return {a.y, -a.x}; }   // multiply by -i

// natural-order in/out 8-point DFT: out[k] = sum_j in[j] W8^{jk}, W8 = e^{-2pi i/8}
__device__ __forceinline__ void fft8(cf a[8]) {
    const float s = 0.70710678118654752f;
    cf b0 = a[0], b1 = a[4], b2 = a[2], b3 = a[6];
    cf b4 = a[1], b5 = a[5], b6 = a[3], b7 = a[7];
    cf c0 = cadd(b0, b1), c1 = csub(b0, b1);
    cf c2 = cadd(b2, b3), c3 = csub(b2, b3);
    cf c4 = cadd(b4, b5), c5 = csub(b4, b5);
    cf c6 = cadd(b6, b7), c7 = csub(b6, b7);
    cf d0 = cadd(c0, c2), d2 = csub(c0, c2);
    cf d1 = cadd(c1, mni(c3)), d3 = csub(c1, mni(c3));
    cf d4 = cadd(c4, c6), d6 = csub(c4, c6);
    cf d5 = cadd(c5, mni(c7)), d7 = csub(c5, mni(c7));
    cf e5 = { s * (d5.x + d5.y), s * (d5.y - d5.x) };   // W8^1 * d5
    cf e6 = mni(d6);                                     // W8^2 * d6
    cf e7 = { s * (d7.y - d7.x), -s * (d7.x + d7.y) };   // W8^3 * d7
    a[0] = cadd(d0, d4); a[4] = csub(d0, d4);
    a[1] = cadd(d1, e5); a[5] = csub(d1, e5);
    a[2] = cadd(d2, e6); a[6] = csub(d2, e6);
    a[3] = cadd(d3, e7); a[7] = csub(d3, e7);
}

__global__ __launch_bounds__(256, 6) void ofdm_mimo_kernel(
    const float* __restrict__ y_data,
    const float* __restrict__ y_ls,
    const int*   __restrict__ x_idx,
    float*       __restrict__ out,
    int B)
{
    // per-wave FFT workspace (float2, padded). After the FFTs, the sb[2..3]
    // rows are reused IN PLACE (as float4) for the pilot LS estimates:
    //   pil[tt][k] = {rr0.re, rr0.im, rr1.re, rr1.im} at float4-slot p4(k).
    __shared__ cf sb[4][544];

    const int tid = threadIdx.x;
    const int q   = tid >> 6;   // wave id = signal id (0,1: data r0,r1; 2,3: ls r0,r1)
    const int t   = tid & 63;   // lane within the FFT
    const int r   = q & 1;
    const int stride = gridDim.x;

    // both Y and Y_l scaled by 1/(N*sqrt(pi)) -- 1/sqrt(pi) on the data path
    // folded into the FFT input (solve is linear in Y).
    const float sc = (float)(1.0 / (512.0 * 0.22627416997969522));

    const float W64A  = -6.2831853071795864769f / 64.0f;
    const float W512A = -6.2831853071795864769f / 512.0f;

    const float lev[4] = {-0.9486832980505138f, -0.31622776601683794f,
                           0.31622776601683794f, 0.9486832980505138f};

    const float* srcp = (q < 2) ? y_data : y_ls;

    // ---- prologue: stage batch-0 inputs into registers ----
    float2 xv[8];
    int idxc[2];
    {
        const int b = blockIdx.x;
        const float2* xin = (const float2*)(srcp + ((size_t)(b * 2 + r) * NTOT + CP) * 2);
        #pragma unroll
        for (int n2 = 0; n2 < 8; ++n2) xv[n2] = xin[t + 64 * n2];
        #pragma unroll
        for (int j = 0; j < 2; ++j)
            idxc[j] = x_idx[((size_t)(b * 2 + j)) * NSC + j + 2 * tid];
    }

    #pragma unroll
    for (int ib = 0; ib < NB; ++ib) {
        const int b = blockIdx.x + ib * stride;

        // ---- stage 1: fft8 over n2 -> k0 (inputs already in registers) ----
        cf a[8];
        #pragma unroll
        for (int n2 = 0; n2 < 8; ++n2) a[n2] = { xv[n2].x * sc, xv[n2].y * sc };
        fft8(a);   // a[k0]

        // twiddle W_64^{n1*k0}: one sincos + power recurrence
        {
            const int n1 = t >> 3;
            float sn, cs;
            __sincosf(W64A * (float)n1, &sn, &cs);
            cf w1 = {cs, sn}, w = w1;
            #pragma unroll
            for (int k0 = 1; k0 < 8; ++k0) {
                a[k0] = cmul(a[k0], w);
                w = cmul(w, w1);
            }
        }
        // T1 write: addr = t*8 + k0; wave-private buffer -> wave barrier only
        #pragma unroll
        for (int k0 = 0; k0 < 8; ++k0) sb[q][p2(t * 8 + k0)] = a[k0];

        // ---- prefetch NEXT batch's inputs: latency hides under stages 2,3 +
        //      pilot + solve of the current batch ----
        float2 xv2[8];
        int idxn[2];
        if (ib + 1 < NB) {
            const int bn = b + stride;
            const float2* xin = (const float2*)(srcp + ((size_t)(bn * 2 + r) * NTOT + CP) * 2);
            #pragma unroll
            for (int n2 = 0; n2 < 8; ++n2) xv2[n2] = xin[t + 64 * n2];
            #pragma unroll
            for (int j = 0; j < 2; ++j)
                idxn[j] = x_idx[((size_t)(bn * 2 + j)) * NSC + j + 2 * tid];
        }
        __builtin_amdgcn_wave_barrier();

        // ---- stage 2: (n0,k0) = (t&7, t>>3); read A'[n0,n1,k0] over n1 ----
        #pragma unroll
        for (int n1 = 0; n1 < 8; ++n1)
            a[n1] = sb[q][p2(n1 * 64 + (t & 7) * 8 + (t >> 3))];
        __builtin_amdgcn_wave_barrier();
        fft8(a);   // a[k1]

        // twiddle W_512^{n0*(k0+8*k1)} = W512^{n0*k0} * (W64^{n0})^{k1}
        {
            const int n0 = t & 7, k0 = t >> 3;
            float sn, cs, sn2, cs2;
            __sincosf(W512A * (float)(n0 * k0), &sn, &cs);
            __sincosf(W64A * (float)n0, &sn2, &cs2);
            cf w = {cs, sn}, st = {cs2, sn2};
            #pragma unroll
            for (int k1 = 0; k1 < 8; ++k1) {
                a[k1] = cmul(a[k1], w);
                w = cmul(w, st);
            }
        }
        // T2 write: addr = n0*64 + k0*8 + k1
        #pragma unroll
        for (int k1 = 0; k1 < 8; ++k1)
            sb[q][p2((t & 7) * 64 + (t >> 3) * 8 + k1)] = a[k1];
        __builtin_amdgcn_wave_barrier();

        // ---- stage 3: (k0,k1) = (t>>3, t&7); read B'[n0,k0,k1] over n0 ----
        #pragma unroll
        for (int n0 = 0; n0 < 8; ++n0)
            a[n0] = sb[q][p2(n0 * 64 + (t >> 3) * 8 + (t & 7))];
        __builtin_amdgcn_wave_barrier();
        fft8(a);   // a[k2]

        // final write: X[k0 + 8*k1 + 64*k2]
        #pragma unroll
        for (int k2 = 0; k2 < 8; ++k2)
            sb[q][p2((t >> 3) + 8 * (t & 7) + 64 * k2)] = a[k2];
        __syncthreads();   // cross-wave: spectra visible to all waves

        // ---- comb pilot LS: pil[tt][rr][k] = Y_l[rr][tt+2k] / x_ls[tt][tt+2k] ----
        float4 pout[2];   // [j] -> packed {rr0.re, rr0.im, rr1.re, rr1.im}
        #pragma unroll
        for (int j = 0; j < 2; ++j) {
            int comb = j + 2 * tid;
            int pc = p2(comb);
            int idx = idxc[j];
            float xr = lev[idx & 3];
            float xi = lev[(idx >> 2) & 3];
            float inv = 1.0f / (xr * xr + xi * xi);
            cf y0l = sb[2][pc];
            cf y1l = sb[3][pc];
            pout[j] = make_float4((y0l.x * xr + y0l.y * xi) * inv,
                                  (y0l.y * xr - y0l.x * xi) * inv,
                                  (y1l.x * xr + y1l.y * xi) * inv,
                                  (y1l.y * xr - y1l.x * xi) * inv);
        }
        __syncthreads();   // all LS-spectra reads done before in-place overwrite
        {
            float4* pilA = (float4*)sb[2];   // tt = 0
            float4* pilB = (float4*)sb[3];   // tt = 1
            pilA[p4(tid)] = pout[0];
            pilB[p4(tid)] = pout[1];
        }
        __syncthreads();

        // ---- per-subcarrier: branchless interp H, fp32 Cramer solve, demap ----
        const float4* pilA = (const float4*)sb[2];
        const float4* pilB = (const float4*)sb[3];
        #pragma unroll
        for (int ni = 0; ni < 2; ++ni) {
            const int n = tid + 256 * ni;
            const int kp = n >> 1;
            const int kR = (kp + 1 < 256) ? kp + 1 : 255;
            const int kL = (kp - 1 > 0) ? kp - 1 : 0;
            const float wA = (n & 1) ? 0.5f : 0.0f;   // t=0 pilots exact at even n
            const float wB = (n & 1) ? 0.0f : 0.5f;   // t=1 pilots exact at odd n

            float4 L0 = pilA[p4(kp)];
            float4 R0 = pilA[p4(kR)];
            float4 R1 = pilB[p4(kp)];
            float4 L1 = pilB[p4(kL)];

            // H[rr][t]; float4 = {rr0.re, rr0.im, rr1.re, rr1.im}
            cf H00 = { L0.x + wA * (R0.x - L0.x), L0.y + wA * (R0.y - L0.y) };
            cf H10 = { L0.z + wA * (R0.z - L0.z), L0.w + wA * (R0.w - L0.w) };
            cf H01 = { R1.x + wB * (L1.x - R1.x), R1.y + wB * (L1.y - R1.y) };
            cf H11 = { R1.z + wB * (L1.z - R1.z), R1.w + wB * (L1.w - R1.w) };

            cf Y0 = sb[0][p2(n)];
            cf Y1 = sb[1][p2(n)];

            cf det  = csub(cmul(H00, H11), cmul(H01, H10));
            cf num0 = csub(cmul(H11, Y0), cmul(H01, Y1));
            cf num1 = csub(cmul(H00, Y1), cmul(H10, Y0));
            float invden = 1.0f / (det.x * det.x + det.y * det.y);
            float X0r = (num0.x * det.x + num0.y * det.y) * invden;
            float X0i = (num0.y * det.x - num0.x * det.y) * invden;
            float X1r = (num1.x * det.x + num1.y * det.y) * invden;
            float X1i = (num1.y * det.x - num1.x * det.y) * invden;

            // x_hat_ri[b][n][t][c] -> flat b*2048 + n*4 + t*2 + c
            *(float4*)(out + (size_t)b * 2048 + (size_t)n * 4) =
                make_float4(X0r, X0i, X1r, X1i);

            // nearest-QAM index per axis (argmin tie -> lower index, hence <=)
            const float bnd = 0.63245553203367587f; // 2/sqrt(10)
            auto qi = [&](float v) -> int {
                return (v <= -bnd) ? 0 : (v <= 0.0f) ? 1 : (v <= bnd) ? 2 : 3;
            };
            int vre0 = qi(X0r), vim0 = qi(X0i);
            int vre1 = qi(X1r), vim1 = qi(X1i);

            // b_hat[b][t][n*4+m] at base B*2048
            size_t bbase = (size_t)B * 2048;
            *(float4*)(out + bbase + ((size_t)b * 2 + 0) * 2048 + (size_t)n * 4) =
                make_float4((float)(vre0 & 1), (float)((vre0 >> 1) & 1),
                            (float)(vim0 & 1), (float)((vim0 >> 1) & 1));
            *(float4*)(out + bbase + ((size_t)b * 2 + 1) * 2048 + (size_t)n * 4) =
                make_float4((float)(vre1 & 1), (float)((vre1 >> 1) & 1),
                            (float)(vim1 & 1), (float)((vim1 >> 1) & 1));
        }

        // ---- rotate pipeline registers, guard sb reuse ----
        if (ib + 1 < NB) {
            __syncthreads();   // solve reads of sb done before next T1 write
            #pragma unroll
            for (int n2 = 0; n2 < 8; ++n2) xv[n2] = xv2[n2];
            idxc[0] = idxn[0];
            idxc[1] = idxn[1];
        }
    }
}

} // namespace

extern "C" void kernel_launch(void* const* d_in, const int* in_sizes, int n_in,
                              void* d_out, int out_size, void* d_ws, size_t ws_size,
                              hipStream_t stream) {
    const float* y_data = (const float*)d_in[0];
    const float* y_ls   = (const float*)d_in[1];
    const int*   x_idx  = (const int*)d_in[2];
    float* out = (float*)d_out;

    int B = in_sizes[0] / (2 * NTOT * 2);   // batch from flat input size
    ofdm_mimo_kernel<<<B / NB, 256, 0, stream>>>(y_data, y_ls, x_idx, out, B);
}

// Round 12
// 33.981 us; speedup vs baseline: 3.0022x; 3.0022x over previous
//
#include <hip/hip_runtime.h>

namespace {

constexpr int NSC  = 512;   // subcarriers
constexpr int CP   = 7;     // cyclic prefix
constexpr int NTOT = 519;   // N + CP

// pad every 16 slots by 1 (works for float2 and float4 granularity)
__device__ __forceinline__ int p2(int x) { return x + (x >> 4); }
__device__ __forceinline__ int p4(int x) { return x + (x >> 4); }

struct cf { float x, y; };
__device__ __forceinline__ cf cadd(cf a, cf b) { return {a.x + b.x, a.y + b.y}; }
__device__ __forceinline__ cf csub(cf a, cf b) { return {a.x - b.x, a.y - b.y}; }
__device__ __forceinline__ cf cmul(cf a, cf b) { return {a.x*b.x - a.y*b.y, a.x*b.y + a.y*b.x}; }
__device__ __forceinline__ cf mni(cf a) { return {a.y, -a.x}; }   // multiply by -i

// natural-order in/out 8-point DFT: out[k] = sum_j in[j] W8^{jk}, W8 = e^{-2pi i/8}
__device__ __forceinline__ void fft8(cf a[8]) {
    const float s = 0.70710678118654752f;
    cf b0 = a[0], b1 = a[4], b2 = a[2], b3 = a[6];
    cf b4 = a[1], b5 = a[5], b6 = a[3], b7 = a[7];
    cf c0 = cadd(b0, b1), c1 = csub(b0, b1);
    cf c2 = cadd(b2, b3), c3 = csub(b2, b3);
    cf c4 = cadd(b4, b5), c5 = csub(b4, b5);
    cf c6 = cadd(b6, b7), c7 = csub(b6, b7);
    cf d0 = cadd(c0, c2), d2 = csub(c0, c2);
    cf d1 = cadd(c1, mni(c3)), d3 = csub(c1, mni(c3));
    cf d4 = cadd(c4, c6), d6 = csub(c4, c6);
    cf d5 = cadd(c5, mni(c7)), d7 = csub(c5, mni(c7));
    cf e5 = { s * (d5.x + d5.y), s * (d5.y - d5.x) };   // W8^1 * d5
    cf e6 = mni(d6);                                     // W8^2 * d6
    cf e7 = { s * (d7.y - d7.x), -s * (d7.x + d7.y) };   // W8^3 * d7
    a[0] = cadd(d0, d4); a[4] = csub(d0, d4);
    a[1] = cadd(d1, e5); a[5] = csub(d1, e5);
    a[2] = cadd(d2, e6); a[6] = csub(d2, e6);
    a[3] = cadd(d3, e7); a[7] = csub(d3, e7);
}

__global__ __launch_bounds__(256, 8) void ofdm_mimo_kernel(
    const float* __restrict__ y_data,
    const float* __restrict__ y_ls,
    const int*   __restrict__ x_idx,
    float*       __restrict__ out,
    int B)
{
    // per-wave FFT workspace (float2, padded). After the FFTs, the sb[2..3]
    // rows are reused IN PLACE (as float4) for the pilot LS estimates:
    //   pil[tt][k] = {rr0.re, rr0.im, rr1.re, rr1.im} at float4-slot p4(k).
    __shared__ cf sb[4][544];

    const int b   = blockIdx.x;
    const int tid = threadIdx.x;
    const int q   = tid >> 6;   // wave id = signal id (0,1: data r0,r1; 2,3: ls r0,r1)
    const int t   = tid & 63;   // lane within the FFT

    // both Y and Y_l scaled by 1/(N*sqrt(pi)) -- 1/sqrt(pi) on the data path
    // folded into the FFT input (solve is linear in Y).
    const float sc = (float)(1.0 / (512.0 * 0.22627416997969522));

    const float W64A  = -6.2831853071795864769f / 64.0f;
    const float W512A = -6.2831853071795864769f / 512.0f;

    // ---- prefetch pilot symbol factors (global loads issued before FFT) ----
    const float lev[4] = {-0.9486832980505138f, -0.31622776601683794f,
                           0.31622776601683794f, 0.9486832980505138f};
    float pxr[2], pxi[2], pinv[2];   // j = 0,1 -> (tt = j, k = tid)
    #pragma unroll
    for (int j = 0; j < 2; ++j) {
        int comb = j + 2 * tid;
        int idx = x_idx[((size_t)(b * 2 + j)) * NSC + comb];
        float xr = lev[idx & 3];
        float xi = lev[(idx >> 2) & 3];
        pxr[j] = xr; pxi[j] = xi;
        pinv[j] = 1.0f / (xr * xr + xi * xi);
    }

    // ---- stage 1: load x[t + 64*n2] (coalesced float2), fft8 over n2 -> k0 ----
    const int r = q & 1;
    const float* srcp = (q < 2) ? y_data : y_ls;
    const float2* xin = (const float2*)(srcp + ((size_t)(b * 2 + r) * NTOT + CP) * 2);

    cf a[8];
    #pragma unroll
    for (int n2 = 0; n2 < 8; ++n2) {
        float2 v = xin[t + 64 * n2];
        a[n2] = { v.x * sc, v.y * sc };
    }
    fft8(a);   // a[k0]

    // twiddle W_64^{n1*k0}: one sincos + power recurrence
    {
        const int n1 = t >> 3;
        float sn, cs;
        __sincosf(W64A * (float)n1, &sn, &cs);
        cf w1 = {cs, sn}, w = w1;
        #pragma unroll
        for (int k0 = 1; k0 < 8; ++k0) {
            a[k0] = cmul(a[k0], w);
            w = cmul(w, w1);
        }
    }
    // T1 write: addr = t*8 + k0; wave-private buffer -> wave barrier only
    #pragma unroll
    for (int k0 = 0; k0 < 8; ++k0) sb[q][p2(t * 8 + k0)] = a[k0];
    __builtin_amdgcn_wave_barrier();

    // ---- stage 2: (n0,k0) = (t&7, t>>3); read A'[n0,n1,k0] over n1 ----
    #pragma unroll
    for (int n1 = 0; n1 < 8; ++n1)
        a[n1] = sb[q][p2(n1 * 64 + (t & 7) * 8 + (t >> 3))];
    __builtin_amdgcn_wave_barrier();
    fft8(a);   // a[k1]

    // twiddle W_512^{n0*(k0+8*k1)} = W512^{n0*k0} * (W64^{n0})^{k1}
    {
        const int n0 = t & 7, k0 = t >> 3;
        float sn, cs, sn2, cs2;
        __sincosf(W512A * (float)(n0 * k0), &sn, &cs);
        __sincosf(W64A * (float)n0, &sn2, &cs2);
        cf w = {cs, sn}, st = {cs2, sn2};
        #pragma unroll
        for (int k1 = 0; k1 < 8; ++k1) {
            a[k1] = cmul(a[k1], w);
            w = cmul(w, st);
        }
    }
    // T2 write: addr = n0*64 + k0*8 + k1
    #pragma unroll
    for (int k1 = 0; k1 < 8; ++k1)
        sb[q][p2((t & 7) * 64 + (t >> 3) * 8 + k1)] = a[k1];
    __builtin_amdgcn_wave_barrier();

    // ---- stage 3: (k0,k1) = (t>>3, t&7); read B'[n0,k0,k1] over n0 ----
    #pragma unroll
    for (int n0 = 0; n0 < 8; ++n0)
        a[n0] = sb[q][p2(n0 * 64 + (t >> 3) * 8 + (t & 7))];
    __builtin_amdgcn_wave_barrier();
    fft8(a);   // a[k2]

    // final write: X[k0 + 8*k1 + 64*k2]
    #pragma unroll
    for (int k2 = 0; k2 < 8; ++k2)
        sb[q][p2((t >> 3) + 8 * (t & 7) + 64 * k2)] = a[k2];
    __syncthreads();   // cross-wave: spectra visible to all waves

    // ---- comb pilot LS: pil[tt][rr][k] = Y_l[rr][tt+2k] / x_ls[tt][tt+2k] ----
    float4 pout[2];   // [j] -> packed {rr0.re, rr0.im, rr1.re, rr1.im}
    #pragma unroll
    for (int j = 0; j < 2; ++j) {
        int comb = j + 2 * tid;
        int pc = p2(comb);
        cf y0l = sb[2][pc];
        cf y1l = sb[3][pc];
        pout[j] = make_float4((y0l.x * pxr[j] + y0l.y * pxi[j]) * pinv[j],
                              (y0l.y * pxr[j] - y0l.x * pxi[j]) * pinv[j],
                              (y1l.x * pxr[j] + y1l.y * pxi[j]) * pinv[j],
                              (y1l.y * pxr[j] - y1l.x * pxi[j]) * pinv[j]);
    }
    __syncthreads();   // all LS-spectra reads done before in-place overwrite
    {
        float4* pilA = (float4*)sb[2];   // tt = 0
        float4* pilB = (float4*)sb[3];   // tt = 1
        pilA[p4(tid)] = pout[0];
        pilB[p4(tid)] = pout[1];
    }
    __syncthreads();

    // ---- per-subcarrier: branchless interp H, fp32 Cramer solve, demap ----
    const float4* pilA = (const float4*)sb[2];
    const float4* pilB = (const float4*)sb[3];
    #pragma unroll
    for (int ni = 0; ni < 2; ++ni) {
        const int n = tid + 256 * ni;
        const int kp = n >> 1;
        const int kR = (kp + 1 < 256) ? kp + 1 : 255;
        const int kL = (kp - 1 > 0) ? kp - 1 : 0;
        const float wA = (n & 1) ? 0.5f : 0.0f;   // t=0 pilots exact at even n
        const float wB = (n & 1) ? 0.0f : 0.5f;   // t=1 pilots exact at odd n

        float4 L0 = pilA[p4(kp)];
        float4 R0 = pilA[p4(kR)];
        float4 R1 = pilB[p4(kp)];
        float4 L1 = pilB[p4(kL)];

        // H[rr][t]; float4 = {rr0.re, rr0.im, rr1.re, rr1.im}
        cf H00 = { L0.x + wA * (R0.x - L0.x), L0.y + wA * (R0.y - L0.y) };
        cf H10 = { L0.z + wA * (R0.z - L0.z), L0.w + wA * (R0.w - L0.w) };
        cf H01 = { R1.x + wB * (L1.x - R1.x), R1.y + wB * (L1.y - R1.y) };
        cf H11 = { R1.z + wB * (L1.z - R1.z), R1.w + wB * (L1.w - R1.w) };

        cf Y0 = sb[0][p2(n)];
        cf Y1 = sb[1][p2(n)];

        cf det  = csub(cmul(H00, H11), cmul(H01, H10));
        cf num0 = csub(cmul(H11, Y0), cmul(H01, Y1));
        cf num1 = csub(cmul(H00, Y1), cmul(H10, Y0));
        float invden = 1.0f / (det.x * det.x + det.y * det.y);
        float X0r = (num0.x * det.x + num0.y * det.y) * invden;
        float X0i = (num0.y * det.x - num0.x * det.y) * invden;
        float X1r = (num1.x * det.x + num1.y * det.y) * invden;
        float X1i = (num1.y * det.x - num1.x * det.y) * invden;

        // x_hat_ri[b][n][t][c] -> flat b*2048 + n*4 + t*2 + c
        *(float4*)(out + (size_t)b * 2048 + (size_t)n * 4) =
            make_float4(X0r, X0i, X1r, X1i);

        // nearest-QAM index per axis (argmin tie -> lower index, hence <=)
        const float bnd = 0.63245553203367587f; // 2/sqrt(10)
        auto qi = [&](float v) -> int {
            return (v <= -bnd) ? 0 : (v <= 0.0f) ? 1 : (v <= bnd) ? 2 : 3;
        };
        int vre0 = qi(X0r), vim0 = qi(X0i);
        int vre1 = qi(X1r), vim1 = qi(X1i);

        // b_hat[b][t][n*4+m] at base B*2048
        size_t bbase = (size_t)B * 2048;
        *(float4*)(out + bbase + ((size_t)b * 2 + 0) * 2048 + (size_t)n * 4) =
            make_float4((float)(vre0 & 1), (float)((vre0 >> 1) & 1),
                        (float)(vim0 & 1), (float)((vim0 >> 1) & 1));
        *(float4*)(out + bbase + ((size_t)b * 2 + 1) * 2048 + (size_t)n * 4) =
            make_float4((float)(vre1 & 1), (float)((vre1 >> 1) & 1),
                        (float)(vim1 & 1), (float)((vim1 >> 1) & 1));
    }
}

} // namespace

extern "C" void kernel_launch(void* const* d_in, const int* in_sizes, int n_in,
                              void* d_out, int out_size, void* d_ws, size_t ws_size,
                              hipStream_t stream) {
    const float* y_data = (const float*)d_in[0];
    const float* y_ls   = (const float*)d_in[1];
    const int*   x_idx  = (const int*)d_in[2];
    float* out = (float*)d_out;

    int B = in_sizes[0] / (2 * NTOT * 2);   // batch from flat input size
    ofdm_mimo_kernel<<<B, 256, 0, stream>>>(y_data, y_ls, x_idx, out, B);
}